// Round 8
// baseline (119.091 us; speedup 1.0000x reference)
//
#include <hip/hip_runtime.h>
#include <math.h>

// Problem constants
#define NT 64
#define NQ 1024
#define NK 1024
// ws layout in floats:
//   KWpack : [1024][32] float4 (vb.x,vb.y,vb.z, sb)      @ 0       (131072 floats)
//   QFpack : [32][1024] float4 (v.x, v.y, v.z, sa)       @ 131072  (131072 floats)
//   wvtab  : [32][8]    (w1L,w2L,w3L,w1A,w2A,w3A,0,0)    @ 262144  (256 floats)
//   KPpack : [1024] float4 (kx,ky,kz,0)                  @ 262400  (4096 floats)
#define WS_KW 0
#define WS_QF 131072
#define WS_WV 262144
#define WS_KP 262400

__launch_bounds__(256)
__global__ void prep_kernel(const float* __restrict__ qfeat,     // [1024][160]
                            const float* __restrict__ keyfeat,   // [1024][160]
                            const float* __restrict__ Wkey,      // [160][160]
                            const float* __restrict__ WvL,       // [96][32]
                            const float* __restrict__ WvA,       // [96][32]
                            const float* __restrict__ kcoord,    // [1024][3]
                            float* __restrict__ ws,
                            float* __restrict__ out) {
  const int blk = blockIdx.x;
  const int tid = threadIdx.x;
  if (blk < 128) {
    // KWpack: row r of key_feat @ W_key, columns (64+3c, 65+3c, 66+3c, c)
    // Only these 128 of 160 output columns are ever consumed downstream.
    const int g = blk * 256 + tid;          // 0..32767
    const int r = g >> 5;
    const int c = g & 31;
    const float* kf = keyfeat + r * 160;
    const int c0 = 64 + 3 * c;
    float a0 = 0.f, a1 = 0.f, a2 = 0.f, a3 = 0.f;
#pragma unroll 4
    for (int k = 0; k < 160; ++k) {
      const float f = kf[k];
      const float* wr = Wkey + k * 160;
      a0 = fmaf(f, wr[c0 + 0], a0);
      a1 = fmaf(f, wr[c0 + 1], a1);
      a2 = fmaf(f, wr[c0 + 2], a2);
      a3 = fmaf(f, wr[c], a3);
    }
    reinterpret_cast<float4*>(ws + WS_KW)[g] = make_float4(a0, a1, a2, a3);
  } else if (blk < 256) {
    // QFpack: (v[p][c], sa[p][c]) stored [c][p] so main-kernel reads coalesce
    const int g = (blk - 128) * 256 + tid;  // 0..32767
    const int p = g >> 5;
    const int c = g & 31;
    const float* q = qfeat + p * 160;
    float4 o = make_float4(q[64 + 3 * c], q[65 + 3 * c], q[66 + 3 * c], q[c]);
    reinterpret_cast<float4*>(ws + WS_QF)[c * 1024 + p] = o;
  } else {
    // (a) zero d_out (harness poisons it 0xAA; main_kernel accumulates atomically)
    out[tid] = 0.f;
    if (tid < 128) out[256 + tid] = 0.f;
    // (b) KPpack: float4 key table for the main kernel's SGPR key stream
    float4* kp = reinterpret_cast<float4*>(ws + WS_KP);
#pragma unroll
    for (int j = 0; j < 4; ++j) {
      const int k = j * 256 + tid;
      kp[k] = make_float4(kcoord[k * 3 + 0], kcoord[k * 3 + 1], kcoord[k * 3 + 2], 0.f);
    }
    // (c) wv means: .mean(axis=-2) over the 32 output channels commutes with
    // the einsum, so each 96->32 channel mix collapses to one 96-vector.
    if (tid < 32) {
      const int c = tid;
      float m0 = 0.f, m1 = 0.f, m2 = 0.f, m3 = 0.f, m4 = 0.f, m5 = 0.f;
      for (int o = 0; o < 32; ++o) {
        m0 += WvL[c * 32 + o];
        m1 += WvL[(32 + c) * 32 + o];
        m2 += WvL[(64 + c) * 32 + o];
        m3 += WvA[c * 32 + o];
        m4 += WvA[(32 + c) * 32 + o];
        m5 += WvA[(64 + c) * 32 + o];
      }
      float* wv = ws + WS_WV + c * 8;
      const float s = 1.0f / 32.0f;
      wv[0] = m0 * s; wv[1] = m1 * s; wv[2] = m2 * s;
      wv[3] = m3 * s; wv[4] = m4 * s; wv[5] = m5 * s;
      wv[6] = 0.f; wv[7] = 0.f;
    }
  }
}

// Block = 64 (t,q) pairs x 4 waves. Wave w scans keys [256w, 256w+256) with a
// WAVE-UNIFORM key index -> keys stream through SGPRs (s_load), so the NN hot
// loop has ZERO LDS/vector-memory traffic (round-7 was LDS-pipe-bound: 16
// waves/CU x 256 ds_read_b128 ~ 17-20us serialized on the shared LDS pipe).
// Tiny LDS cand[4][64] merges the 4 per-wave argmins.
__launch_bounds__(256)
__global__ void main_kernel(const float* __restrict__ T,        // [64][7]
                            const float* __restrict__ qweight,  // [1024]
                            const float* __restrict__ qcoord,   // [1024][3]
                            const float* __restrict__ ws,
                            float* __restrict__ out) {
  __shared__ float2 cand[4][64];  // (d2, idx-bits) per wave per pair
  __shared__ float red[4][8];
  const int tid  = threadIdx.x;
  const int lane = tid & 63;
  const int wu   = __builtin_amdgcn_readfirstlane(tid >> 6);  // wave id, uniform
  const int t    = blockIdx.x >> 4;          // 0..63
  const int pg   = blockIdx.x & 15;          // pair-group within t

  // Load + normalize quaternion (uniform per block)
  const float* Tt = T + t * 7;
  float qw = Tt[0], qx = Tt[1], qy = Tt[2], qz = Tt[3];
  const float Xx = Tt[4], Xy = Tt[5], Xz = Tt[6];
  const float rn = rsqrtf(qw * qw + qx * qx + qy * qy + qz * qz);
  qw *= rn; qx *= rn; qy *= rn; qz *= rn;
  const float ix = -qx, iy = -qy, iz = -qz;  // conjugate (inverse rotation)

  // ---- Phase A: NN over this wave's key quarter, pair pA = pg*64+lane ----
  const int pA = pg * 64 + lane;
  const float qax = qcoord[pA * 3 + 0];
  const float qay = qcoord[pA * 3 + 1];
  const float qaz = qcoord[pA * 3 + 2];
  // Lab-frame transformed query point: qc = quat_apply(q, qp) + X.
  // Subtract-first d2 mirrors the reference's rounding structure (argmin
  // ordering statistic stays at ~ulp(d2) noise).
  const float uvx0 = qy * qaz - qz * qay;
  const float uvy0 = qz * qax - qx * qaz;
  const float uvz0 = qx * qay - qy * qax;
  const float qcx = qax + 2.0f * (qw * uvx0 + (qy * uvz0 - qz * uvy0)) + Xx;
  const float qcy = qay + 2.0f * (qw * uvy0 + (qz * uvx0 - qx * uvz0)) + Xy;
  const float qcz = qaz + 2.0f * (qw * uvz0 + (qx * uvy0 - qy * uvx0)) + Xz;

  const float4* kp = reinterpret_cast<const float4*>(ws + WS_KP);
  const int kbase = wu * 256;                // uniform
  float mv0 = 1e30f, mv1 = 1e30f;
  int mi0 = 0, mi1 = 0;
#pragma unroll 8
  for (int m = 0; m < 256; m += 2) {
    const float4 K0 = kp[kbase + m];         // uniform index -> s_load
    const float4 K1 = kp[kbase + m + 1];
    const float dx0 = qcx - K0.x, dy0 = qcy - K0.y, dz0 = qcz - K0.z;
    const float dx1 = qcx - K1.x, dy1 = qcy - K1.y, dz1 = qcz - K1.z;
    const float d0 = dx0 * dx0 + dy0 * dy0 + dz0 * dz0;
    const float d1 = dx1 * dx1 + dy1 * dy1 + dz1 * dz1;
    if (d0 < mv0) { mv0 = d0; mi0 = kbase + m; }       // strict < keeps lowest k
    if (d1 < mv1) { mv1 = d1; mi1 = kbase + m + 1; }
  }
  float mvA = mv0; int miA = mi0;
  if (mv1 < mvA || (mv1 == mvA && mi1 < miA)) { mvA = mv1; miA = mi1; }
  cand[wu][lane] = make_float2(mvA, __int_as_float(miA));
  __syncthreads();

  // ---- Phase B: merge 4 wave-candidates, then feature math ----
  // Re-map: thread = (pair pF = tid>>2) x (sub = tid&3); lanes of a 4-group
  // pick up the 4 wave-candidates and butterfly-merge (lexicographic = argmin).
  const int pF  = pg * 64 + (tid >> 2);
  const int sub = tid & 3;
  const float2 c0 = cand[sub][tid >> 2];
  float mv = c0.x; int mi = __float_as_int(c0.y);
#pragma unroll
  for (int msk = 1; msk <= 2; msk <<= 1) {
    const float vo = __shfl_xor(mv, msk);
    const int   io = __shfl_xor(mi, msk);
    if (vo < mv || (vo == mv && io < mi)) { mv = vo; mi = io; }
  }
  const int minidx = mi;
  const float env = expf(-sqrtf(mv));

  const float qpx = qcoord[pF * 3 + 0];
  const float qpy = qcoord[pF * 3 + 1];
  const float qpz = qcoord[pF * 3 + 2];

  // Feature math in the query-local frame, 8 channels per thread (c = 4*jj+sub
  // -> 4 lanes of a pair read consecutive float4s, coalesced):
  //   R^T[sa*vb + va'*sb + va' x vb] = sa*(R^T vb) + v*sb + v x (R^T vb)
  const float4* kwrow = reinterpret_cast<const float4*>(ws + WS_KW) + minidx * 32;
  const float4* qfp   = reinterpret_cast<const float4*>(ws + WS_QF) + pF;
  const float* wv = ws + WS_WV;
  float lx = 0.f, ly = 0.f, lz = 0.f, ax = 0.f, ay = 0.f, az = 0.f;
#pragma unroll
  for (int jj = 0; jj < 8; ++jj) {
    const int c = 4 * jj + sub;
    const float4 B = kwrow[c];          // (vb lab-frame, sb), pre-env
    const float4 A = qfp[c * 1024];     // (v local-frame, sa)
    // vb' = R^T vb
    const float uvx = iy * B.z - iz * B.y;
    const float uvy = iz * B.x - ix * B.z;
    const float uvz = ix * B.y - iy * B.x;
    const float bx = B.x + 2.0f * (qw * uvx + (iy * uvz - iz * uvy));
    const float by = B.y + 2.0f * (qw * uvy + (iz * uvx - ix * uvz));
    const float bz = B.z + 2.0f * (qw * uvz + (ix * uvy - iy * uvx));
    // cross(v, vb')
    const float crx = A.y * bz - A.z * by;
    const float cry = A.z * bx - A.x * bz;
    const float crz = A.x * by - A.y * bx;
    const float* w6 = wv + c * 8;
    const float a1L = w6[0] * A.w, a2L = w6[1] * B.w, w3L = w6[2];
    const float a1A = w6[3] * A.w, a2A = w6[4] * B.w, w3A = w6[5];
    lx = fmaf(a1L, bx, fmaf(a2L, A.x, fmaf(w3L, crx, lx)));
    ly = fmaf(a1L, by, fmaf(a2L, A.y, fmaf(w3L, cry, ly)));
    lz = fmaf(a1L, bz, fmaf(a2L, A.z, fmaf(w3L, crz, lz)));
    ax = fmaf(a1A, bx, fmaf(a2A, A.x, fmaf(w3A, crx, ax)));
    ay = fmaf(a1A, by, fmaf(a2A, A.y, fmaf(w3A, cry, ay)));
    az = fmaf(a1A, bz, fmaf(a2A, A.z, fmaf(w3A, crz, az)));
  }
  // 4-lane butterfly sum of channel partials -> all 4 lanes hold full sums
#pragma unroll
  for (int msk = 1; msk <= 2; msk <<= 1) {
    lx += __shfl_xor(lx, msk); ly += __shfl_xor(ly, msk); lz += __shfl_xor(lz, msk);
    ax += __shfl_xor(ax, msk); ay += __shfl_xor(ay, msk); az += __shfl_xor(az, msk);
  }
  // env scales kf linearly -> scales both dtp vector outputs linearly
  lx *= env; ly *= env; lz *= env;
  ax *= env; ay *= env; az *= env;

  // ang_orbital = qp x lin (local frame); weight by query_weight[pF].
  // All 4 lanes of a pair compute identical values; final sum scaled 0.25.
  const float wp = qweight[pF];
  const float ox = qpy * lz - qpz * ly;
  const float oy = qpz * lx - qpx * lz;
  const float oz = qpx * ly - qpy * lx;
  float r0 = wp * lx, r1 = wp * ly, r2 = wp * lz;
  float r3 = wp * (ox + ax), r4 = wp * (oy + ay), r5 = wp * (oz + az);

  // Wave reduce (64 lanes = 16 pairs x 4 identical lanes), block reduce, atomic.
#pragma unroll
  for (int m = 32; m >= 1; m >>= 1) {
    r0 += __shfl_xor(r0, m);
    r1 += __shfl_xor(r1, m);
    r2 += __shfl_xor(r2, m);
    r3 += __shfl_xor(r3, m);
    r4 += __shfl_xor(r4, m);
    r5 += __shfl_xor(r5, m);
  }
  const int wave = tid >> 6;
  const int lane2 = tid & 63;
  if (lane2 == 0) {
    red[wave][0] = r0; red[wave][1] = r1; red[wave][2] = r2;
    red[wave][3] = r3; red[wave][4] = r4; red[wave][5] = r5;
  }
  __syncthreads();
  if (tid < 6) {
    const float s = red[0][tid] + red[1][tid] + red[2][tid] + red[3][tid];
    const int row = (tid < 3) ? (t * 3 + tid) : (192 + t * 3 + (tid - 3));
    atomicAdd(out + row, s * 0.25f);   // 0.25: each pair counted by 4 lanes
  }
}

extern "C" void kernel_launch(void* const* d_in, const int* in_sizes, int n_in,
                              void* d_out, int out_size, void* d_ws, size_t ws_size,
                              hipStream_t stream) {
  const float* T   = (const float*)d_in[0];   // [64][7]
  const float* qw  = (const float*)d_in[1];   // [1024]
  const float* qf  = (const float*)d_in[2];   // [1024][160]
  const float* qc  = (const float*)d_in[3];   // [1024][3]
  const float* kc  = (const float*)d_in[4];   // [1024][3]
  const float* kf  = (const float*)d_in[5];   // [1024][160]
  const float* Wk  = (const float*)d_in[6];   // [160][160]
  const float* WvL = (const float*)d_in[8];   // [96][32]  (Ws_* are dead outputs)
  const float* WvA = (const float*)d_in[10];  // [96][32]
  float* out = (float*)d_out;
  float* ws  = (float*)d_ws;

  prep_kernel<<<257, 256, 0, stream>>>(qf, kf, Wk, WvL, WvA, kc, ws, out);
  main_kernel<<<1024, 256, 0, stream>>>(T, qw, qc, ws, out);
}

// Round 10
// 115.990 us; speedup vs baseline: 1.0267x; 1.0267x over previous
//
#include <hip/hip_runtime.h>
#include <math.h>

// Problem constants
#define NT 64
#define NQ 1024
#define NK 1024
// ws layout in floats:
//   KWpack : [1024][32] float4 (vb.x,vb.y,vb.z, sb)      @ 0       (131072 floats)
//   QFpack : [32][1024] float4 (v.x, v.y, v.z, sa)       @ 131072  (131072 floats)
//   wvtab  : [32][8]    (w1L,w2L,w3L,w1A,w2A,w3A,0,0)    @ 262144  (256 floats)
//   KPpack : [1024] float4 (kx,ky,kz,0)                  @ 262400  (4096 floats)
#define WS_KW 0
#define WS_QF 131072
#define WS_WV 262144
#define WS_KP 262400

__launch_bounds__(256)
__global__ void prep_kernel(const float* __restrict__ qfeat,     // [1024][160]
                            const float* __restrict__ keyfeat,   // [1024][160]
                            const float* __restrict__ Wkey,      // [160][160]
                            const float* __restrict__ WvL,       // [96][32]
                            const float* __restrict__ WvA,       // [96][32]
                            const float* __restrict__ kcoord,    // [1024][3]
                            float* __restrict__ ws,
                            float* __restrict__ out) {
  const int blk = blockIdx.x;
  const int tid = threadIdx.x;
  if (blk < 128) {
    // KWpack: row r of key_feat @ W_key, columns (64+3c, 65+3c, 66+3c, c)
    // Only these 128 of 160 output columns are ever consumed downstream.
    const int g = blk * 256 + tid;          // 0..32767
    const int r = g >> 5;
    const int c = g & 31;
    const float* kf = keyfeat + r * 160;
    const int c0 = 64 + 3 * c;
    float a0 = 0.f, a1 = 0.f, a2 = 0.f, a3 = 0.f;
#pragma unroll 4
    for (int k = 0; k < 160; ++k) {
      const float f = kf[k];
      const float* wr = Wkey + k * 160;
      a0 = fmaf(f, wr[c0 + 0], a0);
      a1 = fmaf(f, wr[c0 + 1], a1);
      a2 = fmaf(f, wr[c0 + 2], a2);
      a3 = fmaf(f, wr[c], a3);
    }
    reinterpret_cast<float4*>(ws + WS_KW)[g] = make_float4(a0, a1, a2, a3);
  } else if (blk < 256) {
    // QFpack: (v[p][c], sa[p][c]) stored [c][p] so main-kernel reads coalesce
    const int g = (blk - 128) * 256 + tid;  // 0..32767
    const int p = g >> 5;
    const int c = g & 31;
    const float* q = qfeat + p * 160;
    float4 o = make_float4(q[64 + 3 * c], q[65 + 3 * c], q[66 + 3 * c], q[c]);
    reinterpret_cast<float4*>(ws + WS_QF)[c * 1024 + p] = o;
  } else {
    // (a) zero d_out (harness poisons it 0xAA; main_kernel accumulates atomically)
    out[tid] = 0.f;
    if (tid < 128) out[256 + tid] = 0.f;
    // (b) KPpack: float4 key table for the main kernel's register key banks
    float4* kp = reinterpret_cast<float4*>(ws + WS_KP);
#pragma unroll
    for (int j = 0; j < 4; ++j) {
      const int k = j * 256 + tid;
      kp[k] = make_float4(kcoord[k * 3 + 0], kcoord[k * 3 + 1], kcoord[k * 3 + 2], 0.f);
    }
    // (c) wv means: .mean(axis=-2) over the 32 output channels commutes with
    // the einsum, so each 96->32 channel mix collapses to one 96-vector.
    if (tid < 32) {
      const int c = tid;
      float m0 = 0.f, m1 = 0.f, m2 = 0.f, m3 = 0.f, m4 = 0.f, m5 = 0.f;
      for (int o = 0; o < 32; ++o) {
        m0 += WvL[c * 32 + o];
        m1 += WvL[(32 + c) * 32 + o];
        m2 += WvL[(64 + c) * 32 + o];
        m3 += WvA[c * 32 + o];
        m4 += WvA[(32 + c) * 32 + o];
        m5 += WvA[(64 + c) * 32 + o];
      }
      float* wv = ws + WS_WV + c * 8;
      const float s = 1.0f / 32.0f;
      wv[0] = m0 * s; wv[1] = m1 * s; wv[2] = m2 * s;
      wv[3] = m3 * s; wv[4] = m4 * s; wv[5] = m5 * s;
      wv[6] = 0.f; wv[7] = 0.f;
    }
  }
}

// Block = 64 (t,q) pairs x 4 waves. Wave w scans keys [256w, 256w+256).
// Keys live in VGPR BANKS (lane l holds keys kbase + b*64 + l); the scan is
// fully unrolled so __builtin_amdgcn_readlane(B, j) with literal j broadcasts
// key j through an SGPR -> the NN hot loop is 12 pure-VALU insts per key with
// ZERO LDS / ZERO VMEM traffic. (Round 7 was LDS-pipe-bound at ~20us/CU;
// round 8's compiler-dependent s_load gamble regressed to ~38us.)
__launch_bounds__(256)
__global__ void main_kernel(const float* __restrict__ T,        // [64][7]
                            const float* __restrict__ qweight,  // [1024]
                            const float* __restrict__ qcoord,   // [1024][3]
                            const float* __restrict__ ws,
                            float* __restrict__ out) {
  __shared__ float2 cand[4][64];  // (d2, idx-bits) per wave per pair
  __shared__ float red[4][8];
  const int tid  = threadIdx.x;
  const int lane = tid & 63;
  const int wu   = __builtin_amdgcn_readfirstlane(tid >> 6);  // wave id, uniform
  const int t    = blockIdx.x >> 4;          // 0..63
  const int pg   = blockIdx.x & 15;          // pair-group within t

  // Load + normalize quaternion (uniform per block)
  const float* Tt = T + t * 7;
  float qw = Tt[0], qx = Tt[1], qy = Tt[2], qz = Tt[3];
  const float Xx = Tt[4], Xy = Tt[5], Xz = Tt[6];
  const float rn = rsqrtf(qw * qw + qx * qx + qy * qy + qz * qz);
  qw *= rn; qx *= rn; qy *= rn; qz *= rn;
  const float ix = -qx, iy = -qy, iz = -qz;  // conjugate (inverse rotation)

  // ---- Phase A: NN over this wave's key quarter, pair pA = pg*64+lane ----
  const int pA = pg * 64 + lane;
  const float qax = qcoord[pA * 3 + 0];
  const float qay = qcoord[pA * 3 + 1];
  const float qaz = qcoord[pA * 3 + 2];
  // Lab-frame transformed query point: qc = quat_apply(q, qp) + X.
  // Subtract-first d2 mirrors the reference's rounding structure (argmin
  // ordering statistic stays at ~ulp(d2) noise).
  const float uvx0 = qy * qaz - qz * qay;
  const float uvy0 = qz * qax - qx * qaz;
  const float uvz0 = qx * qay - qy * qax;
  const float qcx = qax + 2.0f * (qw * uvx0 + (qy * uvz0 - qz * uvy0)) + Xx;
  const float qcy = qay + 2.0f * (qw * uvy0 + (qz * uvx0 - qx * uvz0)) + Xy;
  const float qcz = qaz + 2.0f * (qw * uvz0 + (qx * uvy0 - qy * uvx0)) + Xz;

  // Preload 4 key banks: lane l holds keys kbase + {0,64,128,192} + l.
  const float4* kp = reinterpret_cast<const float4*>(ws + WS_KP);
  const int kbase = wu * 256;                // uniform
  const float4 B0 = kp[kbase + 0 * 64 + lane];
  const float4 B1 = kp[kbase + 1 * 64 + lane];
  const float4 B2 = kp[kbase + 2 * 64 + lane];
  const float4 B3 = kp[kbase + 3 * 64 + lane];

  // Scan banks in ASCENDING key order (bank-major) so strict < keeps the
  // lowest index on ties, matching jnp.argmin first-min semantics.
  float mv = 1e30f;
  int mi = 0;
#define SCAN_BANK(B, boff)                                                      \
  _Pragma("unroll")                                                             \
  for (int j = 0; j < 64; ++j) {                                                \
    const float kx = __int_as_float(                                            \
        __builtin_amdgcn_readlane(__float_as_int((B).x), j));                   \
    const float ky = __int_as_float(                                            \
        __builtin_amdgcn_readlane(__float_as_int((B).y), j));                   \
    const float kz = __int_as_float(                                            \
        __builtin_amdgcn_readlane(__float_as_int((B).z), j));                   \
    const float dx = qcx - kx, dy = qcy - ky, dz = qcz - kz;                    \
    const float d  = dx * dx + dy * dy + dz * dz;                               \
    if (d < mv) { mv = d; mi = kbase + (boff) + j; }                            \
  }
  SCAN_BANK(B0, 0)
  SCAN_BANK(B1, 64)
  SCAN_BANK(B2, 128)
  SCAN_BANK(B3, 192)
#undef SCAN_BANK

  cand[wu][lane] = make_float2(mv, __int_as_float(mi));
  __syncthreads();

  // ---- Phase B: merge 4 wave-candidates, then feature math ----
  // Re-map: thread = (pair pF = tid>>2) x (sub = tid&3); lanes of a 4-group
  // pick up the 4 wave-candidates and butterfly-merge (lexicographic = argmin).
  const int pF  = pg * 64 + (tid >> 2);
  const int sub = tid & 3;
  const float2 c0 = cand[sub][tid >> 2];
  float mvB = c0.x; int miB = __float_as_int(c0.y);
#pragma unroll
  for (int msk = 1; msk <= 2; msk <<= 1) {
    const float vo = __shfl_xor(mvB, msk);
    const int   io = __shfl_xor(miB, msk);
    if (vo < mvB || (vo == mvB && io < miB)) { mvB = vo; miB = io; }
  }
  const int minidx = miB;
  const float env = expf(-sqrtf(mvB));

  const float qpx = qcoord[pF * 3 + 0];
  const float qpy = qcoord[pF * 3 + 1];
  const float qpz = qcoord[pF * 3 + 2];

  // Feature math in the query-local frame, 8 channels per thread (c = 4*jj+sub
  // -> 4 lanes of a pair read consecutive float4s, coalesced):
  //   R^T[sa*vb + va'*sb + va' x vb] = sa*(R^T vb) + v*sb + v x (R^T vb)
  const float4* kwrow = reinterpret_cast<const float4*>(ws + WS_KW) + minidx * 32;
  const float4* qfp   = reinterpret_cast<const float4*>(ws + WS_QF) + pF;
  const float* wv = ws + WS_WV;
  float lx = 0.f, ly = 0.f, lz = 0.f, ax = 0.f, ay = 0.f, az = 0.f;
#pragma unroll
  for (int jj = 0; jj < 8; ++jj) {
    const int c = 4 * jj + sub;
    const float4 B = kwrow[c];          // (vb lab-frame, sb), pre-env
    const float4 A = qfp[c * 1024];     // (v local-frame, sa)
    // vb' = R^T vb
    const float uvx = iy * B.z - iz * B.y;
    const float uvy = iz * B.x - ix * B.z;
    const float uvz = ix * B.y - iy * B.x;
    const float bx = B.x + 2.0f * (qw * uvx + (iy * uvz - iz * uvy));
    const float by = B.y + 2.0f * (qw * uvy + (iz * uvx - ix * uvz));
    const float bz = B.z + 2.0f * (qw * uvz + (ix * uvy - iy * uvx));
    // cross(v, vb')
    const float crx = A.y * bz - A.z * by;
    const float cry = A.z * bx - A.x * bz;
    const float crz = A.x * by - A.y * bx;
    const float* w6 = wv + c * 8;
    const float a1L = w6[0] * A.w, a2L = w6[1] * B.w, w3L = w6[2];
    const float a1A = w6[3] * A.w, a2A = w6[4] * B.w, w3A = w6[5];
    lx = fmaf(a1L, bx, fmaf(a2L, A.x, fmaf(w3L, crx, lx)));
    ly = fmaf(a1L, by, fmaf(a2L, A.y, fmaf(w3L, cry, ly)));
    lz = fmaf(a1L, bz, fmaf(a2L, A.z, fmaf(w3L, crz, lz)));
    ax = fmaf(a1A, bx, fmaf(a2A, A.x, fmaf(w3A, crx, ax)));
    ay = fmaf(a1A, by, fmaf(a2A, A.y, fmaf(w3A, cry, ay)));
    az = fmaf(a1A, bz, fmaf(a2A, A.z, fmaf(w3A, crz, az)));
  }
  // 4-lane butterfly sum of channel partials -> all 4 lanes hold full sums
#pragma unroll
  for (int msk = 1; msk <= 2; msk <<= 1) {
    lx += __shfl_xor(lx, msk); ly += __shfl_xor(ly, msk); lz += __shfl_xor(lz, msk);
    ax += __shfl_xor(ax, msk); ay += __shfl_xor(ay, msk); az += __shfl_xor(az, msk);
  }
  // env scales kf linearly -> scales both dtp vector outputs linearly
  lx *= env; ly *= env; lz *= env;
  ax *= env; ay *= env; az *= env;

  // ang_orbital = qp x lin (local frame); weight by query_weight[pF].
  // All 4 lanes of a pair compute identical values; final sum scaled 0.25.
  const float wp = qweight[pF];
  const float ox = qpy * lz - qpz * ly;
  const float oy = qpz * lx - qpx * lz;
  const float oz = qpx * ly - qpy * lx;
  float r0 = wp * lx, r1 = wp * ly, r2 = wp * lz;
  float r3 = wp * (ox + ax), r4 = wp * (oy + ay), r5 = wp * (oz + az);

  // Wave reduce (64 lanes = 16 pairs x 4 identical lanes), block reduce, atomic.
#pragma unroll
  for (int m = 32; m >= 1; m >>= 1) {
    r0 += __shfl_xor(r0, m);
    r1 += __shfl_xor(r1, m);
    r2 += __shfl_xor(r2, m);
    r3 += __shfl_xor(r3, m);
    r4 += __shfl_xor(r4, m);
    r5 += __shfl_xor(r5, m);
  }
  const int wave = tid >> 6;
  const int lane2 = tid & 63;
  if (lane2 == 0) {
    red[wave][0] = r0; red[wave][1] = r1; red[wave][2] = r2;
    red[wave][3] = r3; red[wave][4] = r4; red[wave][5] = r5;
  }
  __syncthreads();
  if (tid < 6) {
    const float s = red[0][tid] + red[1][tid] + red[2][tid] + red[3][tid];
    const int row = (tid < 3) ? (t * 3 + tid) : (192 + t * 3 + (tid - 3));
    atomicAdd(out + row, s * 0.25f);   // 0.25: each pair counted by 4 lanes
  }
}

extern "C" void kernel_launch(void* const* d_in, const int* in_sizes, int n_in,
                              void* d_out, int out_size, void* d_ws, size_t ws_size,
                              hipStream_t stream) {
  const float* T   = (const float*)d_in[0];   // [64][7]
  const float* qw  = (const float*)d_in[1];   // [1024]
  const float* qf  = (const float*)d_in[2];   // [1024][160]
  const float* qc  = (const float*)d_in[3];   // [1024][3]
  const float* kc  = (const float*)d_in[4];   // [1024][3]
  const float* kf  = (const float*)d_in[5];   // [1024][160]
  const float* Wk  = (const float*)d_in[6];   // [160][160]
  const float* WvL = (const float*)d_in[8];   // [96][32]  (Ws_* are dead outputs)
  const float* WvA = (const float*)d_in[10];  // [96][32]
  float* out = (float*)d_out;
  float* ws  = (float*)d_ws;

  prep_kernel<<<257, 256, 0, stream>>>(qf, kf, Wk, WvL, WvA, kc, ws, out);
  main_kernel<<<1024, 256, 0, stream>>>(T, qw, qc, ws, out);
}

// Round 11
// 107.076 us; speedup vs baseline: 1.1122x; 1.0833x over previous
//
#include <hip/hip_runtime.h>
#include <math.h>

// Problem constants
#define NT 64
#define NQ 1024
#define NK 1024
// ws layout in floats:
//   KWpack : [1024][32] float4 (vb.x,vb.y,vb.z, sb)      @ 0       (131072 floats)
//   QFpack : [32][1024] float4 (v.x, v.y, v.z, sa)       @ 131072  (131072 floats)
//   wvtab  : [32][8]    (w1L,w2L,w3L,w1A,w2A,w3A,0,0)    @ 262144  (256 floats)
//   KPpack : [1024] float4 (kx,ky,kz,0)                  @ 262400  (4096 floats)
#define WS_KW 0
#define WS_QF 131072
#define WS_WV 262144
#define WS_KP 262400

__launch_bounds__(256)
__global__ void prep_kernel(const float* __restrict__ qfeat,     // [1024][160]
                            const float* __restrict__ keyfeat,   // [1024][160]
                            const float* __restrict__ Wkey,      // [160][160]
                            const float* __restrict__ WvL,       // [96][32]
                            const float* __restrict__ WvA,       // [96][32]
                            const float* __restrict__ kcoord,    // [1024][3]
                            float* __restrict__ ws,
                            float* __restrict__ out) {
  const int blk = blockIdx.x;
  const int tid = threadIdx.x;
  if (blk < 128) {
    // KWpack: row r of key_feat @ W_key, columns (64+3c, 65+3c, 66+3c, c)
    // Only these 128 of 160 output columns are ever consumed downstream.
    const int g = blk * 256 + tid;          // 0..32767
    const int r = g >> 5;
    const int c = g & 31;
    const float* kf = keyfeat + r * 160;
    const int c0 = 64 + 3 * c;
    float a0 = 0.f, a1 = 0.f, a2 = 0.f, a3 = 0.f;
#pragma unroll 4
    for (int k = 0; k < 160; ++k) {
      const float f = kf[k];
      const float* wr = Wkey + k * 160;
      a0 = fmaf(f, wr[c0 + 0], a0);
      a1 = fmaf(f, wr[c0 + 1], a1);
      a2 = fmaf(f, wr[c0 + 2], a2);
      a3 = fmaf(f, wr[c], a3);
    }
    reinterpret_cast<float4*>(ws + WS_KW)[g] = make_float4(a0, a1, a2, a3);
  } else if (blk < 256) {
    // QFpack: (v[p][c], sa[p][c]) stored [c][p] so main-kernel reads coalesce
    const int g = (blk - 128) * 256 + tid;  // 0..32767
    const int p = g >> 5;
    const int c = g & 31;
    const float* q = qfeat + p * 160;
    float4 o = make_float4(q[64 + 3 * c], q[65 + 3 * c], q[66 + 3 * c], q[c]);
    reinterpret_cast<float4*>(ws + WS_QF)[c * 1024 + p] = o;
  } else {
    // (a) zero d_out (harness poisons it 0xAA; main_kernel accumulates atomically)
    out[tid] = 0.f;
    if (tid < 128) out[256 + tid] = 0.f;
    // (b) KPpack: float4 key table staged into LDS by the main kernel
    float4* kp = reinterpret_cast<float4*>(ws + WS_KP);
#pragma unroll
    for (int j = 0; j < 4; ++j) {
      const int k = j * 256 + tid;
      kp[k] = make_float4(kcoord[k * 3 + 0], kcoord[k * 3 + 1], kcoord[k * 3 + 2], 0.f);
    }
    // (c) wv means: .mean(axis=-2) over the 32 output channels commutes with
    // the einsum, so each 96->32 channel mix collapses to one 96-vector.
    if (tid < 32) {
      const int c = tid;
      float m0 = 0.f, m1 = 0.f, m2 = 0.f, m3 = 0.f, m4 = 0.f, m5 = 0.f;
      for (int o = 0; o < 32; ++o) {
        m0 += WvL[c * 32 + o];
        m1 += WvL[(32 + c) * 32 + o];
        m2 += WvL[(64 + c) * 32 + o];
        m3 += WvA[c * 32 + o];
        m4 += WvA[(32 + c) * 32 + o];
        m5 += WvA[(64 + c) * 32 + o];
      }
      float* wv = ws + WS_WV + c * 8;
      const float s = 1.0f / 32.0f;
      wv[0] = m0 * s; wv[1] = m1 * s; wv[2] = m2 * s;
      wv[3] = m3 * s; wv[4] = m4 * s; wv[5] = m5 * s;
      wv[6] = 0.f; wv[7] = 0.f;
    }
  }
}

// Block = 128 (t,q) pairs x 4 waves; 512 blocks = 2 blocks/CU, 2 waves/SIMD.
// Phase A: wave w scans keys [256w,256w+256) from LDS with WAVE-UNIFORM
// broadcast ds_read_b128, each thread serving TWO queries (Q=2) -> DS-pipe
// work per CU is HALF of the round-7 Q=1 layout (8 waves x 256 reads x 12cy
// ~ 10us, balanced against ~7.7us/SIMD VALU). Round-10's readlane variant
// regressed (I$-fetch + SGPR hazards); keys stay on the DS pipe, amortized.
__launch_bounds__(256)
__global__ void main_kernel(const float* __restrict__ T,        // [64][7]
                            const float* __restrict__ qweight,  // [1024]
                            const float* __restrict__ qcoord,   // [1024][3]
                            const float* __restrict__ ws,
                            float* __restrict__ out) {
  __shared__ float4 keys[1024];    // 16 KB staged keys
  __shared__ float2 cand[4][128];  // (d2, idx-bits) per wave per pair
  __shared__ float red[4][8];
  const int tid  = threadIdx.x;
  const int lane = tid & 63;
  const int wu   = __builtin_amdgcn_readfirstlane(tid >> 6);  // wave id, uniform
  const int t    = blockIdx.x >> 3;          // 0..63
  const int pg   = blockIdx.x & 7;           // pair-group within t (128 pairs)

  // Stage keys (coalesced float4 reads from ws KPpack)
  {
    const float4* kp = reinterpret_cast<const float4*>(ws + WS_KP);
#pragma unroll
    for (int j = 0; j < 4; ++j) keys[j * 256 + tid] = kp[j * 256 + tid];
  }

  // Load + normalize quaternion (uniform per block)
  const float* Tt = T + t * 7;
  float qw = Tt[0], qx = Tt[1], qy = Tt[2], qz = Tt[3];
  const float Xx = Tt[4], Xy = Tt[5], Xz = Tt[6];
  const float rn = rsqrtf(qw * qw + qx * qx + qy * qy + qz * qz);
  qw *= rn; qx *= rn; qy *= rn; qz *= rn;
  const float ix = -qx, iy = -qy, iz = -qz;  // conjugate (inverse rotation)

  // ---- Phase A: two queries per thread ----
  const int qA = pg * 128 + lane;
  const int qB = qA + 64;
  const float qax = qcoord[qA * 3 + 0], qay = qcoord[qA * 3 + 1], qaz = qcoord[qA * 3 + 2];
  const float qbx = qcoord[qB * 3 + 0], qby = qcoord[qB * 3 + 1], qbz = qcoord[qB * 3 + 2];
  // Lab-frame transformed query points: qc = quat_apply(q, qp) + X.
  // Subtract-first d2 mirrors the reference's rounding structure.
  const float uax = qy * qaz - qz * qay, uay = qz * qax - qx * qaz, uaz = qx * qay - qy * qax;
  const float qcax = qax + 2.0f * (qw * uax + (qy * uaz - qz * uay)) + Xx;
  const float qcay = qay + 2.0f * (qw * uay + (qz * uax - qx * uaz)) + Xy;
  const float qcaz = qaz + 2.0f * (qw * uaz + (qx * uay - qy * uax)) + Xz;
  const float ubx = qy * qbz - qz * qby, uby = qz * qbx - qx * qbz, ubz = qx * qby - qy * qbx;
  const float qcbx = qbx + 2.0f * (qw * ubx + (qy * ubz - qz * uby)) + Xx;
  const float qcby = qby + 2.0f * (qw * uby + (qz * ubx - qx * ubz)) + Xy;
  const float qcbz = qbz + 2.0f * (qw * ubz + (qx * uby - qy * ubx)) + Xz;

  __syncthreads();

  // Scan this wave's quarter in ASCENDING key order; strict < keeps the
  // lowest index on ties (jnp.argmin first-min semantics).
  const int kbase = wu * 256;                // uniform
  float mvA = 1e30f, mvB = 1e30f;
  int miA = 0, miB = 0;
#pragma unroll 8
  for (int m = 0; m < 256; ++m) {
    const float4 K = keys[kbase + m];        // uniform addr -> broadcast read
    const float dax = qcax - K.x, day = qcay - K.y, daz = qcaz - K.z;
    const float dbx = qcbx - K.x, dby = qcby - K.y, dbz = qcbz - K.z;
    const float dA = dax * dax + day * day + daz * daz;
    const float dB = dbx * dbx + dby * dby + dbz * dbz;
    if (dA < mvA) { mvA = dA; miA = kbase + m; }
    if (dB < mvB) { mvB = dB; miB = kbase + m; }
  }
  cand[wu][lane]      = make_float2(mvA, __int_as_float(miA));
  cand[wu][64 + lane] = make_float2(mvB, __int_as_float(miB));
  __syncthreads();

  // ---- Phase B: merge 4 wave-candidates, then feature math ----
  // 2 threads per pair: pl = tid>>1 (0..127), sub = tid&1. Thread sub merges
  // quarters {2sub, 2sub+1}; one shfl_xor(1) completes the lexicographic
  // (val, idx) argmin across all 4 quarters.
  const int pl  = tid >> 1;
  const int sub = tid & 1;
  const float2 ca = cand[2 * sub][pl];
  const float2 cb = cand[2 * sub + 1][pl];
  float mv = ca.x; int mi = __float_as_int(ca.y);
  {
    const float vb2 = cb.x; const int ib2 = __float_as_int(cb.y);
    if (vb2 < mv || (vb2 == mv && ib2 < mi)) { mv = vb2; mi = ib2; }
  }
  {
    const float vo = __shfl_xor(mv, 1);
    const int   io = __shfl_xor(mi, 1);
    if (vo < mv || (vo == mv && io < mi)) { mv = vo; mi = io; }
  }
  const int minidx = mi;
  const float env = expf(-sqrtf(mv));

  const int pF = pg * 128 + pl;
  const float qpx = qcoord[pF * 3 + 0];
  const float qpy = qcoord[pF * 3 + 1];
  const float qpz = qcoord[pF * 3 + 2];

  // Feature math in the query-local frame, 16 channels per thread
  // (c = 2*jj + sub -> the 2 lanes of a pair read consecutive float4s):
  //   R^T[sa*vb + va'*sb + va' x vb] = sa*(R^T vb) + v*sb + v x (R^T vb)
  const float4* kwrow = reinterpret_cast<const float4*>(ws + WS_KW) + minidx * 32;
  const float4* qfp   = reinterpret_cast<const float4*>(ws + WS_QF) + pF;
  const float* wv = ws + WS_WV;
  float lx = 0.f, ly = 0.f, lz = 0.f, ax = 0.f, ay = 0.f, az = 0.f;
#pragma unroll
  for (int jj = 0; jj < 16; ++jj) {
    const int c = 2 * jj + sub;
    const float4 B = kwrow[c];          // (vb lab-frame, sb), pre-env
    const float4 A = qfp[c * 1024];     // (v local-frame, sa)
    // vb' = R^T vb
    const float uvx = iy * B.z - iz * B.y;
    const float uvy = iz * B.x - ix * B.z;
    const float uvz = ix * B.y - iy * B.x;
    const float bx = B.x + 2.0f * (qw * uvx + (iy * uvz - iz * uvy));
    const float by = B.y + 2.0f * (qw * uvy + (iz * uvx - ix * uvz));
    const float bz = B.z + 2.0f * (qw * uvz + (ix * uvy - iy * uvx));
    // cross(v, vb')
    const float crx = A.y * bz - A.z * by;
    const float cry = A.z * bx - A.x * bz;
    const float crz = A.x * by - A.y * bx;
    const float* w6 = wv + c * 8;
    const float a1L = w6[0] * A.w, a2L = w6[1] * B.w, w3L = w6[2];
    const float a1A = w6[3] * A.w, a2A = w6[4] * B.w, w3A = w6[5];
    lx = fmaf(a1L, bx, fmaf(a2L, A.x, fmaf(w3L, crx, lx)));
    ly = fmaf(a1L, by, fmaf(a2L, A.y, fmaf(w3L, cry, ly)));
    lz = fmaf(a1L, bz, fmaf(a2L, A.z, fmaf(w3L, crz, lz)));
    ax = fmaf(a1A, bx, fmaf(a2A, A.x, fmaf(w3A, crx, ax)));
    ay = fmaf(a1A, by, fmaf(a2A, A.y, fmaf(w3A, cry, ay)));
    az = fmaf(a1A, bz, fmaf(a2A, A.z, fmaf(w3A, crz, az)));
  }
  // one butterfly step sums the 2 channel-halves -> both lanes hold full sums
  lx += __shfl_xor(lx, 1); ly += __shfl_xor(ly, 1); lz += __shfl_xor(lz, 1);
  ax += __shfl_xor(ax, 1); ay += __shfl_xor(ay, 1); az += __shfl_xor(az, 1);
  // env scales kf linearly -> scales both dtp vector outputs linearly
  lx *= env; ly *= env; lz *= env;
  ax *= env; ay *= env; az *= env;

  // ang_orbital = qp x lin (local frame); weight by query_weight[pF].
  // Both lanes of a pair hold identical values; final sum scaled 0.5.
  const float wp = qweight[pF];
  const float ox = qpy * lz - qpz * ly;
  const float oy = qpz * lx - qpx * lz;
  const float oz = qpx * ly - qpy * lx;
  float r0 = wp * lx, r1 = wp * ly, r2 = wp * lz;
  float r3 = wp * (ox + ax), r4 = wp * (oy + ay), r5 = wp * (oz + az);

  // Wave reduce (64 lanes = 32 pairs x 2 identical lanes), block reduce, atomic.
#pragma unroll
  for (int m = 32; m >= 1; m >>= 1) {
    r0 += __shfl_xor(r0, m);
    r1 += __shfl_xor(r1, m);
    r2 += __shfl_xor(r2, m);
    r3 += __shfl_xor(r3, m);
    r4 += __shfl_xor(r4, m);
    r5 += __shfl_xor(r5, m);
  }
  if (lane == 0) {
    red[wu][0] = r0; red[wu][1] = r1; red[wu][2] = r2;
    red[wu][3] = r3; red[wu][4] = r4; red[wu][5] = r5;
  }
  __syncthreads();
  if (tid < 6) {
    const float s = red[0][tid] + red[1][tid] + red[2][tid] + red[3][tid];
    const int row = (tid < 3) ? (t * 3 + tid) : (192 + t * 3 + (tid - 3));
    atomicAdd(out + row, s * 0.5f);   // 0.5: each pair counted by 2 lanes
  }
}

extern "C" void kernel_launch(void* const* d_in, const int* in_sizes, int n_in,
                              void* d_out, int out_size, void* d_ws, size_t ws_size,
                              hipStream_t stream) {
  const float* T   = (const float*)d_in[0];   // [64][7]
  const float* qw  = (const float*)d_in[1];   // [1024]
  const float* qf  = (const float*)d_in[2];   // [1024][160]
  const float* qc  = (const float*)d_in[3];   // [1024][3]
  const float* kc  = (const float*)d_in[4];   // [1024][3]
  const float* kf  = (const float*)d_in[5];   // [1024][160]
  const float* Wk  = (const float*)d_in[6];   // [160][160]
  const float* WvL = (const float*)d_in[8];   // [96][32]  (Ws_* are dead outputs)
  const float* WvA = (const float*)d_in[10];  // [96][32]
  float* out = (float*)d_out;
  float* ws  = (float*)d_ws;

  prep_kernel<<<257, 256, 0, stream>>>(qf, kf, Wk, WvL, WvA, kc, ws, out);
  main_kernel<<<512, 256, 0, stream>>>(T, qw, qc, ws, out);
}